// Round 14
// baseline (358.841 us; speedup 1.0000x reference)
//
#include <hip/hip_runtime.h>

// UIR_KG round 14 — r13 with the degree-perm fused INTO row_sort (intra-
// partition counting sort by degree). r13 evidence: perm helps pull0
// 118->104us but its 3 setup kernels (+launches) cost ~15us. row_sort
// already has per-row degrees in hist[]; sorting rows by degree within
// each 512-row partition keeps within-block degree equality (the barrier-
// wait fix) AND pairs-read locality (block's ranges in one ~130KB window).
// deg_count/deg_scan/deg_scatter + dcnt memset deleted.
//
// ws: pairs int2[NE] | row_end int[N] | small(pcnt,pbase,gcur)
//     | Ebf u16[N*64] | x1b u16[N*32] | perm int[N]

constexpr int PSHIFT = 9;             // 512 rows per partition -> P=293
constexpr int PROWS  = 1 << PSHIFT;
constexpr int PBINS  = 512;
constexpr int GF_T   = 1024;
constexpr int GF_E   = 4096;
constexpr int GF_K   = GF_E / GF_T;

static __device__ __forceinline__ float leaky(float v) {
    return v > 0.0f ? v : 0.01f * v;
}

static __device__ __forceinline__ unsigned short f2bf_rne(float f) {
    unsigned u = __float_as_uint(f);
    return (unsigned short)((u + 0x7FFF + ((u >> 16) & 1)) >> 16);
}

static __device__ __forceinline__ void unpack2(unsigned u, float& lo, float& hi) {
    lo = __uint_as_float(u << 16);
    hi = __uint_as_float(u & 0xFFFF0000u);
}

static __device__ __forceinline__ unsigned pack2(float lo, float hi) {
    return ((unsigned)f2bf_rne(hi) << 16) | (unsigned)f2bf_rne(lo);
}

// ---------------- out[:,0:64] = E, and Ebf = bf16(E) ----------------
__global__ void copy_E_kernel(const float* __restrict__ E, float* __restrict__ out,
                              unsigned short* __restrict__ Ebf, int N) {
    int tid = blockIdx.x * blockDim.x + threadIdx.x;
    if (tid >= N * 16) return;
    int i = tid >> 4, g = tid & 15;
    float4 v = reinterpret_cast<const float4*>(E)[(size_t)i * 16 + g];
    *reinterpret_cast<float4*>(out + (size_t)i * 112 + g * 4) = v;
    if (Ebf) {
        ushort4 b;
        b.x = f2bf_rne(v.x); b.y = f2bf_rne(v.y);
        b.z = f2bf_rne(v.z); b.w = f2bf_rne(v.w);
        *reinterpret_cast<ushort4*>(Ebf + (size_t)i * 64 + g * 4) = b;
    }
}

// ---------------- global partition histogram (LDS-binned) ----------------
__global__ void part_hist_kernel(const int* __restrict__ rows, int* __restrict__ pcnt,
                                 int NE, int P) {
    extern __shared__ int h[];
    for (int i = threadIdx.x; i < P; i += blockDim.x) h[i] = 0;
    __syncthreads();
    for (int e = blockIdx.x * blockDim.x + threadIdx.x; e < NE; e += gridDim.x * blockDim.x)
        atomicAdd(&h[rows[e] >> PSHIFT], 1);
    __syncthreads();
    for (int i = threadIdx.x; i < P; i += blockDim.x) {
        int c = h[i];
        if (c) atomicAdd(&pcnt[i], c);
    }
}

// ---------------- scan partition counts -> pbase[P+1], gcur ----------------
__global__ __launch_bounds__(PBINS) void part_scan_kernel(
    const int* __restrict__ pcnt, int* __restrict__ pbase,
    int* __restrict__ gcur, int P, int NE) {
    __shared__ int s[PBINS];
    int v = (threadIdx.x < (unsigned)P) ? pcnt[threadIdx.x] : 0;
    s[threadIdx.x] = v;
    __syncthreads();
    for (int off = 1; off < PBINS; off <<= 1) {
        int t = (threadIdx.x >= (unsigned)off) ? s[threadIdx.x - off] : 0;
        __syncthreads();
        s[threadIdx.x] += t;
        __syncthreads();
    }
    if (threadIdx.x < (unsigned)P) {
        int ex = s[threadIdx.x] - v;
        pbase[threadIdx.x] = ex;
        gcur[threadIdx.x]  = ex;
    }
    if (threadIdx.x == 0) pbase[P] = NE;
}

// ---------------- LDS group + contiguous flush ----------------
__global__ __launch_bounds__(GF_T) void group_flush_kernel(
    const int* __restrict__ rows, const int* __restrict__ cols,
    const float* __restrict__ ev, int* __restrict__ gcur,
    int2* __restrict__ tmp, int NE, int P) {
    __shared__ int2 staged[GF_E];
    __shared__ unsigned short sp[GF_E];
    __shared__ int hist[PBINS], runstart[PBINS], hcur[PBINS], gbase[PBINS], scanb[PBINS];

    int e0  = blockIdx.x * GF_E;
    int cnt = min(GF_E, NE - e0);

    if (threadIdx.x < PBINS) hist[threadIdx.x] = 0;
    __syncthreads();

    int pk[GF_K], ck[GF_K], rk[GF_K];
    float vk[GF_K];
#pragma unroll
    for (int k = 0; k < GF_K; k++) {
        int idx = threadIdx.x + k * GF_T;
        if (idx < cnt) {
            int r = rows[e0 + idx];
            pk[k] = r >> PSHIFT;
            rk[k] = r & (PROWS - 1);
            ck[k] = cols[e0 + idx];
            vk[k] = ev[e0 + idx];
            atomicAdd(&hist[pk[k]], 1);
        } else pk[k] = -1;
    }
    __syncthreads();
    if (threadIdx.x < PBINS) scanb[threadIdx.x] = hist[threadIdx.x];
    __syncthreads();
    for (int off = 1; off < PBINS; off <<= 1) {
        int t = 0;
        if (threadIdx.x < PBINS && threadIdx.x >= (unsigned)off) t = scanb[threadIdx.x - off];
        __syncthreads();
        if (threadIdx.x < PBINS) scanb[threadIdx.x] += t;
        __syncthreads();
    }
    if (threadIdx.x < PBINS) {
        int ex = scanb[threadIdx.x] - hist[threadIdx.x];
        runstart[threadIdx.x] = ex;
        hcur[threadIdx.x]     = ex;
    }
    __syncthreads();
#pragma unroll
    for (int k = 0; k < GF_K; k++) {
        if (pk[k] >= 0) {
            int slot = atomicAdd(&hcur[pk[k]], 1);
            staged[slot] = make_int2(ck[k] | (rk[k] << 18), __float_as_int(vk[k]));
            sp[slot] = (unsigned short)pk[k];
        }
    }
    __syncthreads();
    if (threadIdx.x < (unsigned)P) {
        int h = hist[threadIdx.x];
        if (h > 0) gbase[threadIdx.x] = atomicAdd(&gcur[threadIdx.x], h);
    }
    __syncthreads();
#pragma unroll
    for (int k = 0; k < GF_K; k++) {
        int i = threadIdx.x + k * GF_T;
        if (i < cnt) {
            int p = sp[i];
            tmp[gbase[p] + (i - runstart[p])] = staged[i];
        }
    }
}

// ---------------- per-partition row sort + fused degree-perm ----------------
// Emits: pairs (row-sorted), row_end CSR, and perm[] = rows of this partition
// sorted by degree (intra-partition counting sort, 256 bins).
__global__ __launch_bounds__(PROWS) void row_sort_kernel(
    const int2* __restrict__ tmp, int2* __restrict__ pairs,
    const int* __restrict__ pbase, int* __restrict__ row_end,
    int* __restrict__ perm, int N) {
    __shared__ int hist[PROWS], cur[PROWS], scanb[PROWS];
    __shared__ int dh[256], dbase[256];
    int p     = blockIdx.x;
    int start = pbase[p];
    int end   = pbase[p + 1];
    int tid   = threadIdx.x;
    hist[tid] = 0;
    if (tid < 256) dh[tid] = 0;
    __syncthreads();
    for (int e = start + tid; e < end; e += PROWS)
        atomicAdd(&hist[tmp[e].x >> 18], 1);
    __syncthreads();
    scanb[tid] = hist[tid];
    __syncthreads();
    for (int off = 1; off < PROWS; off <<= 1) {
        int t = (tid >= (unsigned)off) ? scanb[tid - off] : 0;
        __syncthreads();
        scanb[tid] += t;
        __syncthreads();
    }
    int inc = scanb[tid];
    cur[tid] = start + inc - hist[tid];
    int row = (p << PSHIFT) + tid;
    bool valid = row < N;
    if (valid) row_end[row] = start + inc;

    // ---- fused degree-perm: counting sort of this partition's rows ----
    int bin = min(hist[tid], 255);
    if (valid) atomicAdd(&dh[bin], 1);
    __syncthreads();
    if (tid < 256) scanb[tid] = dh[tid];   // scanb free (inc is in a register)
    __syncthreads();
    for (int off = 1; off < 256; off <<= 1) {
        int t = 0;
        if (tid < 256 && tid >= (unsigned)off) t = scanb[tid - off];
        __syncthreads();
        if (tid < 256) scanb[tid] += t;
        __syncthreads();
    }
    if (tid < 256) dbase[tid] = scanb[tid] - dh[tid];  // exclusive base
    __syncthreads();
    if (valid) {
        int slot = atomicAdd(&dbase[bin], 1);
        perm[(p << PSHIFT) + slot] = row;   // dense: partition p owns slots p*512..
    }
    __syncthreads();

    // ---- scatter pairs into row order ----
    for (int e = start + tid; e < end; e += PROWS) {
        int2 t = tmp[e];
        int pos = atomicAdd(&cur[t.x >> 18], 1);
        pairs[pos] = make_int2(t.x & 0x3FFFF, t.y);
    }
}

// ---------------- all-bf16 pull + bi-interaction layer (perm-scheduled) ----------------
template<int DIN, int DOUT>
__global__ __launch_bounds__(256) void pull_layer_b2_kernel(
    const unsigned short* __restrict__ xb,   // bf16 [N][DIN]
    const int2* __restrict__ pairs, const int* __restrict__ row_end,
    const int* __restrict__ perm,
    const float* __restrict__ W1, const float* __restrict__ b1,
    const float* __restrict__ W2, const float* __restrict__ b2,
    unsigned short* __restrict__ xnextb,     // bf16 [N][DOUT] or null
    float* __restrict__ out, int out_col0, int N) {
    constexpr int Q   = DIN / 8;
    constexpr int RPB = 256 / Q;
    constexpr int LDU = DIN + 8;
    constexpr int LDW = DIN + 4;

    __shared__ float sW1[DOUT * LDW];
    __shared__ float sW2[DOUT * LDW];
    __shared__ unsigned short hb[2][RPB][LDU];

    for (int idx = threadIdx.x; idx < DOUT * DIN; idx += 256) {
        int j = idx / DIN, k = idx % DIN;
        sW1[j * LDW + k] = W1[idx];
        sW2[j * LDW + k] = W2[idx];
    }

    int lr  = threadIdx.x / Q;
    int q   = threadIdx.x % Q;
    int idx = blockIdx.x * RPB + lr;
    int row = (idx < N) ? perm[idx] : -1;   // degree-balanced schedule

    if (row >= 0) {
        int start = row ? row_end[row - 1] : 0;
        int end   = row_end[row];
        const uint4* xbv = reinterpret_cast<const uint4*>(xb);
        float acc[8] = {0.f, 0.f, 0.f, 0.f, 0.f, 0.f, 0.f, 0.f};
        int e = start;
        for (; e + 3 < end; e += 4) {  // 4 gathers in flight (16B each)
            int2 p[4]; uint4 g[4];
#pragma unroll
            for (int k = 0; k < 4; k++) p[k] = pairs[e + k];
#pragma unroll
            for (int k = 0; k < 4; k++) g[k] = xbv[(size_t)p[k].x * Q + q];
#pragma unroll
            for (int k = 0; k < 4; k++) {
                float v = __int_as_float(p[k].y);
                float lo, hi;
                unpack2(g[k].x, lo, hi); acc[0] += v * lo; acc[1] += v * hi;
                unpack2(g[k].y, lo, hi); acc[2] += v * lo; acc[3] += v * hi;
                unpack2(g[k].z, lo, hi); acc[4] += v * lo; acc[5] += v * hi;
                unpack2(g[k].w, lo, hi); acc[6] += v * lo; acc[7] += v * hi;
            }
        }
        for (; e < end; e++) {
            int2 p0 = pairs[e];
            uint4 g0 = xbv[(size_t)p0.x * Q + q];
            float v0 = __int_as_float(p0.y);
            float lo, hi;
            unpack2(g0.x, lo, hi); acc[0] += v0 * lo; acc[1] += v0 * hi;
            unpack2(g0.y, lo, hi); acc[2] += v0 * lo; acc[3] += v0 * hi;
            unpack2(g0.z, lo, hi); acc[4] += v0 * lo; acc[5] += v0 * hi;
            unpack2(g0.w, lo, hi); acc[6] += v0 * lo; acc[7] += v0 * hi;
        }
        uint4 xr = xbv[(size_t)row * Q + q];
        float xf[8];
        unpack2(xr.x, xf[0], xf[1]);
        unpack2(xr.y, xf[2], xf[3]);
        unpack2(xr.z, xf[4], xf[5]);
        unpack2(xr.w, xf[6], xf[7]);
        uint4 s1, s2;
        s1.x = pack2(xf[0] + acc[0], xf[1] + acc[1]);
        s1.y = pack2(xf[2] + acc[2], xf[3] + acc[3]);
        s1.z = pack2(xf[4] + acc[4], xf[5] + acc[5]);
        s1.w = pack2(xf[6] + acc[6], xf[7] + acc[7]);
        s2.x = pack2(xf[0] * acc[0], xf[1] * acc[1]);
        s2.y = pack2(xf[2] * acc[2], xf[3] * acc[3]);
        s2.z = pack2(xf[4] * acc[4], xf[5] * acc[5]);
        s2.w = pack2(xf[6] * acc[6], xf[7] * acc[7]);
        *reinterpret_cast<uint4*>(&hb[0][lr][q * 8]) = s1;
        *reinterpret_cast<uint4*>(&hb[1][lr][q * 8]) = s2;
    }
    __syncthreads();
    if (row < 0) return;

    // interleaved outputs: j = q + Q*jj (conflict-free W reads)
    float a1[4], a2[4];
#pragma unroll
    for (int jj = 0; jj < 4; jj++) {
        a1[jj] = b1[q + Q * jj];
        a2[jj] = b2[q + Q * jj];
    }
    const uint4* h1r = reinterpret_cast<const uint4*>(&hb[0][lr][0]);
    const uint4* h2r = reinterpret_cast<const uint4*>(&hb[1][lr][0]);
#pragma unroll
    for (int c = 0; c < DIN / 8; c++) {
        uint4 u1 = h1r[c], u2 = h2r[c];
        float f1[8], f2[8];
        unpack2(u1.x, f1[0], f1[1]); unpack2(u1.y, f1[2], f1[3]);
        unpack2(u1.z, f1[4], f1[5]); unpack2(u1.w, f1[6], f1[7]);
        unpack2(u2.x, f2[0], f2[1]); unpack2(u2.y, f2[2], f2[3]);
        unpack2(u2.z, f2[4], f2[5]); unpack2(u2.w, f2[6], f2[7]);
#pragma unroll
        for (int jj = 0; jj < 4; jj++) {
            int j = q + Q * jj;
            const float4* w1p = reinterpret_cast<const float4*>(&sW1[j * LDW + c * 8]);
            const float4* w2p = reinterpret_cast<const float4*>(&sW2[j * LDW + c * 8]);
            float4 wa = w1p[0], wb = w1p[1];
            float4 wc = w2p[0], wd = w2p[1];
            a1[jj] += f1[0] * wa.x + f1[1] * wa.y + f1[2] * wa.z + f1[3] * wa.w
                    + f1[4] * wb.x + f1[5] * wb.y + f1[6] * wb.z + f1[7] * wb.w;
            a2[jj] += f2[0] * wc.x + f2[1] * wc.y + f2[2] * wc.z + f2[3] * wc.w
                    + f2[4] * wd.x + f2[5] * wd.y + f2[6] * wd.z + f2[7] * wd.w;
        }
    }
    float y[4], nrm = 0.f;
#pragma unroll
    for (int jj = 0; jj < 4; jj++) {
        y[jj] = leaky(a1[jj]) + leaky(a2[jj]);
        nrm += y[jj] * y[jj];
    }
#pragma unroll
    for (int m = 1; m < Q; m <<= 1) nrm += __shfl_xor(nrm, m, 64);
    float inv = 1.0f / fmaxf(sqrtf(nrm), 1e-12f);
    if (xnextb) {
#pragma unroll
        for (int jj = 0; jj < 4; jj++)
            xnextb[(size_t)row * DOUT + q + Q * jj] = f2bf_rne(y[jj]);
    }
    float* o = out + (size_t)row * 112 + out_col0;
#pragma unroll
    for (int jj = 0; jj < 4; jj++) o[q + Q * jj] = y[jj] * inv;
}

// ---------------- f32 pull + layer (tiny-ws fallback) ----------------
template<int DIN, int DOUT>
__global__ __launch_bounds__(256) void pull_layer_kernel(
    const float* __restrict__ x, const int2* __restrict__ pairs,
    const int* __restrict__ row_end,
    const float* __restrict__ W1, const float* __restrict__ b1,
    const float* __restrict__ W2, const float* __restrict__ b2,
    float* __restrict__ xnext, float* __restrict__ out, int out_col0, int N) {
    constexpr int Q   = DIN / 4;
    constexpr int RPB = 256 / Q;
    constexpr int LD  = DIN + 4;
    constexpr int LD4 = LD / 4;
    static_assert(DOUT == 2 * Q, "thread owns exactly 2 output dims");

    __shared__ float sW1[DOUT * LD];
    __shared__ float sW2[DOUT * LD];
    __shared__ float hb[2][RPB][LD];

    for (int idx = threadIdx.x; idx < DOUT * DIN; idx += 256) {
        int j = idx / DIN, k = idx % DIN;
        sW1[j * LD + k] = W1[idx];
        sW2[j * LD + k] = W2[idx];
    }

    int lr  = threadIdx.x / Q;
    int q   = threadIdx.x % Q;
    int row = blockIdx.x * RPB + lr;

    if (row < N) {
        int start = row ? row_end[row - 1] : 0;
        int end   = row_end[row];
        const float4* xv = reinterpret_cast<const float4*>(x);
        float4 acc = make_float4(0.f, 0.f, 0.f, 0.f);
        int e = start;
        for (; e + 3 < end; e += 4) {
            int2 p0 = pairs[e];
            int2 p1 = pairs[e + 1];
            int2 p2 = pairs[e + 2];
            int2 p3 = pairs[e + 3];
            float4 g0 = xv[(size_t)p0.x * Q + q];
            float4 g1 = xv[(size_t)p1.x * Q + q];
            float4 g2 = xv[(size_t)p2.x * Q + q];
            float4 g3 = xv[(size_t)p3.x * Q + q];
            float v0 = __int_as_float(p0.y), v1 = __int_as_float(p1.y);
            float v2 = __int_as_float(p2.y), v3 = __int_as_float(p3.y);
            acc.x += v0 * g0.x; acc.y += v0 * g0.y; acc.z += v0 * g0.z; acc.w += v0 * g0.w;
            acc.x += v1 * g1.x; acc.y += v1 * g1.y; acc.z += v1 * g1.z; acc.w += v1 * g1.w;
            acc.x += v2 * g2.x; acc.y += v2 * g2.y; acc.z += v2 * g2.z; acc.w += v2 * g2.w;
            acc.x += v3 * g3.x; acc.y += v3 * g3.y; acc.z += v3 * g3.z; acc.w += v3 * g3.w;
        }
        for (; e < end; e++) {
            int2 p0 = pairs[e];
            float4 g0 = xv[(size_t)p0.x * Q + q];
            float v0 = __int_as_float(p0.y);
            acc.x += v0 * g0.x; acc.y += v0 * g0.y; acc.z += v0 * g0.z; acc.w += v0 * g0.w;
        }
        float4 xr = xv[(size_t)row * Q + q];
        float4 h1 = make_float4(xr.x + acc.x, xr.y + acc.y, xr.z + acc.z, xr.w + acc.w);
        float4 h2 = make_float4(xr.x * acc.x, xr.y * acc.y, xr.z * acc.z, xr.w * acc.w);
        *reinterpret_cast<float4*>(&hb[0][lr][q * 4]) = h1;
        *reinterpret_cast<float4*>(&hb[1][lr][q * 4]) = h2;
    }
    __syncthreads();
    if (row >= N) return;

    float a0 = b1[q], a1 = b1[q + Q], a2 = b2[q], a3 = b2[q + Q];
    const float4* w1v = reinterpret_cast<const float4*>(sW1);
    const float4* w2v = reinterpret_cast<const float4*>(sW2);
    const float4* h1v = reinterpret_cast<const float4*>(&hb[0][lr][0]);
    const float4* h2v = reinterpret_cast<const float4*>(&hb[1][lr][0]);
#pragma unroll
    for (int k4 = 0; k4 < DIN / 4; k4++) {
        float4 h1 = h1v[k4];
        float4 h2 = h2v[k4];
        float4 wa = w1v[q * LD4 + k4];
        float4 wb = w1v[(q + Q) * LD4 + k4];
        float4 wc = w2v[q * LD4 + k4];
        float4 wd = w2v[(q + Q) * LD4 + k4];
        a0 += h1.x * wa.x + h1.y * wa.y + h1.z * wa.z + h1.w * wa.w;
        a1 += h1.x * wb.x + h1.y * wb.y + h1.z * wb.z + h1.w * wb.w;
        a2 += h2.x * wc.x + h2.y * wc.y + h2.z * wc.z + h2.w * wc.w;
        a3 += h2.x * wd.x + h2.y * wd.y + h2.z * wd.z + h2.w * wd.w;
    }
    float y0 = leaky(a0) + leaky(a2);
    float y1 = leaky(a1) + leaky(a3);
    float nrm = y0 * y0 + y1 * y1;
#pragma unroll
    for (int m = 1; m < Q; m <<= 1) nrm += __shfl_xor(nrm, m, 64);
    float inv = 1.0f / fmaxf(sqrtf(nrm), 1e-12f);
    if (xnext) {
        xnext[(size_t)row * DOUT + q]     = y0;
        xnext[(size_t)row * DOUT + q + Q] = y1;
    }
    float* o = out + (size_t)row * 112 + out_col0;
    o[q]     = y0 * inv;
    o[q + Q] = y1 * inv;
}

extern "C" void kernel_launch(void* const* d_in, const int* in_sizes, int n_in,
                              void* d_out, int out_size, void* d_ws, size_t ws_size,
                              hipStream_t stream) {
    const float* Eemb = (const float*)d_in[0];
    const float* ev   = (const float*)d_in[1];
    const int*   rows = (const int*)d_in[2];
    const int*   cols = (const int*)d_in[3];
    const float* W1_0 = (const float*)d_in[4];
    const float* b1_0 = (const float*)d_in[5];
    const float* W2_0 = (const float*)d_in[6];
    const float* b2_0 = (const float*)d_in[7];
    const float* W1_1 = (const float*)d_in[8];
    const float* b1_1 = (const float*)d_in[9];
    const float* W2_1 = (const float*)d_in[10];
    const float* b2_1 = (const float*)d_in[11];
    float* out = (float*)d_out;

    int N  = in_sizes[0] / 64;
    int NE = in_sizes[1];
    int P  = (N + PROWS - 1) >> PSHIFT;   // 293

    size_t pairs_b  = (size_t)NE * sizeof(int2);
    size_t rowend_b = ((size_t)N * sizeof(int) + 255) & ~(size_t)255;
    size_t small_b  = (PBINS + (PBINS + 1) + PBINS) * sizeof(int) + 256;
    small_b = (small_b + 255) & ~(size_t)255;
    size_t ebf_b    = ((size_t)N * 64 * sizeof(unsigned short) + 255) & ~(size_t)255;
    size_t x1b_b    = ((size_t)N * 32 * sizeof(unsigned short) + 255) & ~(size_t)255;
    size_t perm_b   = (size_t)N * sizeof(int);

    char* base = (char*)d_ws;
    int2*  pairs   = (int2*)base;
    int*   row_end = (int*)(base + pairs_b);
    int*   pcnt    = (int*)(base + pairs_b + rowend_b);
    int*   pbase   = pcnt + PBINS;
    int*   gcur    = pbase + PBINS + 1;
    unsigned short* Ebf = (unsigned short*)(base + pairs_b + rowend_b + small_b);
    unsigned short* x1b = (unsigned short*)(base + pairs_b + rowend_b + small_b + ebf_b);
    int*   perm    = (int*)(base + pairs_b + rowend_b + small_b + ebf_b + x1b_b);
    float* x1      = (float*)(base + pairs_b + rowend_b + small_b);  // fallback layout

    bool use_bf = ws_size >= pairs_b + rowend_b + small_b + ebf_b + x1b_b + perm_b;

    int2* tmp = (int2*)d_out;  // 38.4MB scratch, dead until copy_E

    hipMemsetAsync(pcnt, 0, PBINS * sizeof(int), stream);
    part_hist_kernel<<<256, 1024, P * sizeof(int), stream>>>(rows, pcnt, NE, P);
    part_scan_kernel<<<1, PBINS, 0, stream>>>(pcnt, pbase, gcur, P, NE);
    group_flush_kernel<<<(NE + GF_E - 1) / GF_E, GF_T, 0, stream>>>(
        rows, cols, ev, gcur, tmp, NE, P);
    row_sort_kernel<<<P, PROWS, 0, stream>>>(tmp, pairs, pbase, row_end,
                                             use_bf ? perm : row_end /*dummy*/, N);

    copy_E_kernel<<<(N * 16 + 255) / 256, 256, 0, stream>>>(
        Eemb, out, use_bf ? Ebf : nullptr, N);

    if (use_bf) {
        pull_layer_b2_kernel<64, 32><<<(N + 31) / 32, 256, 0, stream>>>(
            Ebf, pairs, row_end, perm, W1_0, b1_0, W2_0, b2_0, x1b, out, 64, N);
        pull_layer_b2_kernel<32, 16><<<(N + 63) / 64, 256, 0, stream>>>(
            x1b, pairs, row_end, perm, W1_1, b1_1, W2_1, b2_1, nullptr, out, 96, N);
    } else {
        pull_layer_kernel<64, 32><<<(N + 15) / 16, 256, 0, stream>>>(
            Eemb, pairs, row_end, W1_0, b1_0, W2_0, b2_0, x1, out, 64, N);
        pull_layer_kernel<32, 16><<<(N + 31) / 32, 256, 0, stream>>>(
            x1, pairs, row_end, W1_1, b1_1, W2_1, b2_1, nullptr, out, 96, N);
    }
}

// Round 15
// 337.504 us; speedup vs baseline: 1.0632x; 1.0632x over previous
//
#include <hip/hip_runtime.h>

// UIR_KG round 15 — r13 (global degree-sort perm, proven pull0=104us) with:
//  (a) deg_count fused into row_sort (row degrees already in hist[]);
//  (b) wave-shfl 3-phase scans replacing Hillis-Steele in group_flush and
//      row_sort (18 block barriers -> 2 per scan);
//  (c) r14's intra-partition perm REVERTED (regressed 104->125us on pull0).
//
// ws: pairs int2[NE] | row_end int[N] | small(pcnt,pbase,gcur,dcnt,dcur)
//     | Ebf u16[N*64] | x1b u16[N*32] | perm int[N]

constexpr int PSHIFT = 9;             // 512 rows per partition -> P=293
constexpr int PROWS  = 1 << PSHIFT;
constexpr int PBINS  = 512;
constexpr int GF_T   = 1024;
constexpr int GF_E   = 4096;
constexpr int GF_K   = GF_E / GF_T;
constexpr int DS_T   = 1024;          // deg_scatter threads
constexpr int DS_R   = 4096;          // rows per deg_scatter block

static __device__ __forceinline__ float leaky(float v) {
    return v > 0.0f ? v : 0.01f * v;
}

static __device__ __forceinline__ unsigned short f2bf_rne(float f) {
    unsigned u = __float_as_uint(f);
    return (unsigned short)((u + 0x7FFF + ((u >> 16) & 1)) >> 16);
}

static __device__ __forceinline__ void unpack2(unsigned u, float& lo, float& hi) {
    lo = __uint_as_float(u << 16);
    hi = __uint_as_float(u & 0xFFFF0000u);
}

static __device__ __forceinline__ unsigned pack2(float lo, float hi) {
    return ((unsigned)f2bf_rne(hi) << 16) | (unsigned)f2bf_rne(lo);
}

// ---------------- out[:,0:64] = E, and Ebf = bf16(E) ----------------
__global__ void copy_E_kernel(const float* __restrict__ E, float* __restrict__ out,
                              unsigned short* __restrict__ Ebf, int N) {
    int tid = blockIdx.x * blockDim.x + threadIdx.x;
    if (tid >= N * 16) return;
    int i = tid >> 4, g = tid & 15;
    float4 v = reinterpret_cast<const float4*>(E)[(size_t)i * 16 + g];
    *reinterpret_cast<float4*>(out + (size_t)i * 112 + g * 4) = v;
    if (Ebf) {
        ushort4 b;
        b.x = f2bf_rne(v.x); b.y = f2bf_rne(v.y);
        b.z = f2bf_rne(v.z); b.w = f2bf_rne(v.w);
        *reinterpret_cast<ushort4*>(Ebf + (size_t)i * 64 + g * 4) = b;
    }
}

// ---------------- global partition histogram (LDS-binned) ----------------
__global__ void part_hist_kernel(const int* __restrict__ rows, int* __restrict__ pcnt,
                                 int NE, int P) {
    extern __shared__ int h[];
    for (int i = threadIdx.x; i < P; i += blockDim.x) h[i] = 0;
    __syncthreads();
    for (int e = blockIdx.x * blockDim.x + threadIdx.x; e < NE; e += gridDim.x * blockDim.x)
        atomicAdd(&h[rows[e] >> PSHIFT], 1);
    __syncthreads();
    for (int i = threadIdx.x; i < P; i += blockDim.x) {
        int c = h[i];
        if (c) atomicAdd(&pcnt[i], c);
    }
}

// ---------------- scan partition counts -> pbase[P+1], gcur ----------------
__global__ __launch_bounds__(PBINS) void part_scan_kernel(
    const int* __restrict__ pcnt, int* __restrict__ pbase,
    int* __restrict__ gcur, int P, int NE) {
    __shared__ int s[PBINS];
    int v = (threadIdx.x < (unsigned)P) ? pcnt[threadIdx.x] : 0;
    s[threadIdx.x] = v;
    __syncthreads();
    for (int off = 1; off < PBINS; off <<= 1) {
        int t = (threadIdx.x >= (unsigned)off) ? s[threadIdx.x - off] : 0;
        __syncthreads();
        s[threadIdx.x] += t;
        __syncthreads();
    }
    if (threadIdx.x < (unsigned)P) {
        int ex = s[threadIdx.x] - v;
        pbase[threadIdx.x] = ex;
        gcur[threadIdx.x]  = ex;
    }
    if (threadIdx.x == 0) pbase[P] = NE;
}

// ---------------- LDS group + contiguous flush (wave-shfl scan) ----------------
__global__ __launch_bounds__(GF_T) void group_flush_kernel(
    const int* __restrict__ rows, const int* __restrict__ cols,
    const float* __restrict__ ev, int* __restrict__ gcur,
    int2* __restrict__ tmp, int NE, int P) {
    __shared__ int2 staged[GF_E];
    __shared__ unsigned short sp[GF_E];
    __shared__ int hist[PBINS], runstart[PBINS], hcur[PBINS], gbase[PBINS];
    __shared__ int wsum[PBINS / 64], woff[PBINS / 64];

    int e0  = blockIdx.x * GF_E;
    int cnt = min(GF_E, NE - e0);
    int tid = threadIdx.x, lane = tid & 63;

    if (tid < PBINS) hist[tid] = 0;
    __syncthreads();

    int pk[GF_K], ck[GF_K], rk[GF_K];
    float vk[GF_K];
#pragma unroll
    for (int k = 0; k < GF_K; k++) {
        int idx = tid + k * GF_T;
        if (idx < cnt) {
            int r = rows[e0 + idx];
            pk[k] = r >> PSHIFT;
            rk[k] = r & (PROWS - 1);
            ck[k] = cols[e0 + idx];
            vk[k] = ev[e0 + idx];
            atomicAdd(&hist[pk[k]], 1);
        } else pk[k] = -1;
    }
    __syncthreads();
    // wave-shfl exclusive scan over PBINS (=512) bins
    {
        int v = (tid < PBINS) ? hist[tid] : 0;
        int inc = v;
#pragma unroll
        for (int off = 1; off < 64; off <<= 1) {
            int t = __shfl_up(inc, off, 64);
            if (lane >= off) inc += t;
        }
        if (tid < PBINS && lane == 63) wsum[tid >> 6] = inc;
        __syncthreads();
        if (tid < PBINS / 64) {
            int a = 0;
            for (int i = 0; i < tid; i++) a += wsum[i];
            woff[tid] = a;
        }
        __syncthreads();
        if (tid < PBINS) {
            int ex = inc - v + woff[tid >> 6];
            runstart[tid] = ex;
            hcur[tid]     = ex;
        }
    }
    __syncthreads();
#pragma unroll
    for (int k = 0; k < GF_K; k++) {
        if (pk[k] >= 0) {
            int slot = atomicAdd(&hcur[pk[k]], 1);
            staged[slot] = make_int2(ck[k] | (rk[k] << 18), __float_as_int(vk[k]));
            sp[slot] = (unsigned short)pk[k];
        }
    }
    __syncthreads();
    if (tid < (unsigned)P) {
        int h = hist[tid];
        if (h > 0) gbase[tid] = atomicAdd(&gcur[tid], h);
    }
    __syncthreads();
#pragma unroll
    for (int k = 0; k < GF_K; k++) {
        int i = tid + k * GF_T;
        if (i < cnt) {
            int p = sp[i];
            tmp[gbase[p] + (i - runstart[p])] = staged[i];
        }
    }
}

// ---------------- per-partition row sort + fused global degree hist ----------------
__global__ __launch_bounds__(PROWS) void row_sort_kernel(
    const int2* __restrict__ tmp, int2* __restrict__ pairs,
    const int* __restrict__ pbase, int* __restrict__ row_end,
    int* __restrict__ dcnt, int N) {
    __shared__ int hist[PROWS], cur[PROWS];
    __shared__ int wsum[PROWS / 64], woff[PROWS / 64], dh[256];
    int p     = blockIdx.x;
    int start = pbase[p];
    int end   = pbase[p + 1];
    int tid   = threadIdx.x, lane = tid & 63, w = tid >> 6;
    hist[tid] = 0;
    if (tid < 256) dh[tid] = 0;
    __syncthreads();
    for (int e = start + tid; e < end; e += PROWS)
        atomicAdd(&hist[tmp[e].x >> 18], 1);
    __syncthreads();
    int v = hist[tid];
    // wave-shfl inclusive scan over PROWS (=512) rows
    int inc = v;
#pragma unroll
    for (int off = 1; off < 64; off <<= 1) {
        int t = __shfl_up(inc, off, 64);
        if (lane >= off) inc += t;
    }
    if (lane == 63) wsum[w] = inc;
    __syncthreads();
    if (tid < PROWS / 64) {
        int a = 0;
        for (int i = 0; i < tid; i++) a += wsum[i];
        woff[tid] = a;
    }
    __syncthreads();
    int incg = inc + woff[w];               // global inclusive within partition
    cur[tid] = start + incg - v;            // exclusive base
    int row   = (p << PSHIFT) + tid;
    bool valid = row < N;
    if (valid) row_end[row] = start + incg;
    if (valid && dcnt) atomicAdd(&dh[min(v, 255)], 1);  // fused deg_count
    __syncthreads();
    if (dcnt && tid < 256) {
        int c = dh[tid];
        if (c) atomicAdd(&dcnt[tid], c);
    }
    for (int e = start + tid; e < end; e += PROWS) {
        int2 t = tmp[e];
        int pos = atomicAdd(&cur[t.x >> 18], 1);
        pairs[pos] = make_int2(t.x & 0x3FFFF, t.y);
    }
}

// ---------------- degree scan + LDS-staged global deg scatter (r13) ----------------
__global__ void deg_scan_kernel(const int* __restrict__ dcnt, int* __restrict__ dcur) {
    __shared__ int s[256];
    int v = dcnt[threadIdx.x];   // blockDim == 256
    s[threadIdx.x] = v;
    __syncthreads();
    for (int off = 1; off < 256; off <<= 1) {
        int t = (threadIdx.x >= (unsigned)off) ? s[threadIdx.x - off] : 0;
        __syncthreads();
        s[threadIdx.x] += t;
        __syncthreads();
    }
    dcur[threadIdx.x] = s[threadIdx.x] - v;  // exclusive
}

__global__ __launch_bounds__(DS_T) void deg_scatter_kernel(
    const int* __restrict__ row_end, int* __restrict__ dcur,
    int* __restrict__ perm, int N) {
    __shared__ int h[256], hcur[256], gbase[256];
    int r0  = blockIdx.x * DS_R;
    int cnt = min(DS_R, N - r0);
    if (threadIdx.x < 256) { h[threadIdx.x] = 0; hcur[threadIdx.x] = 0; }
    __syncthreads();
    int dk[DS_R / DS_T];
#pragma unroll
    for (int k = 0; k < DS_R / DS_T; k++) {
        int i = threadIdx.x + k * DS_T;
        if (i < cnt) {
            int r = r0 + i;
            int d = row_end[r] - (r ? row_end[r - 1] : 0);
            dk[k] = min(d, 255);
            atomicAdd(&h[dk[k]], 1);
        } else dk[k] = -1;
    }
    __syncthreads();
    if (threadIdx.x < 256) {
        int c = h[threadIdx.x];
        if (c > 0) gbase[threadIdx.x] = atomicAdd(&dcur[threadIdx.x], c);
    }
    __syncthreads();
#pragma unroll
    for (int k = 0; k < DS_R / DS_T; k++) {
        int i = threadIdx.x + k * DS_T;
        if (dk[k] >= 0) {
            int rank = atomicAdd(&hcur[dk[k]], 1);
            perm[gbase[dk[k]] + rank] = r0 + i;  // 0.6MB L2-hot window
        }
    }
}

// ---------------- all-bf16 pull + bi-interaction layer (perm-scheduled) ----------------
template<int DIN, int DOUT>
__global__ __launch_bounds__(256) void pull_layer_b2_kernel(
    const unsigned short* __restrict__ xb,   // bf16 [N][DIN]
    const int2* __restrict__ pairs, const int* __restrict__ row_end,
    const int* __restrict__ perm,
    const float* __restrict__ W1, const float* __restrict__ b1,
    const float* __restrict__ W2, const float* __restrict__ b2,
    unsigned short* __restrict__ xnextb,     // bf16 [N][DOUT] or null
    float* __restrict__ out, int out_col0, int N) {
    constexpr int Q   = DIN / 8;
    constexpr int RPB = 256 / Q;
    constexpr int LDU = DIN + 8;
    constexpr int LDW = DIN + 4;

    __shared__ float sW1[DOUT * LDW];
    __shared__ float sW2[DOUT * LDW];
    __shared__ unsigned short hb[2][RPB][LDU];

    for (int idx = threadIdx.x; idx < DOUT * DIN; idx += 256) {
        int j = idx / DIN, k = idx % DIN;
        sW1[j * LDW + k] = W1[idx];
        sW2[j * LDW + k] = W2[idx];
    }

    int lr  = threadIdx.x / Q;
    int q   = threadIdx.x % Q;
    int idx = blockIdx.x * RPB + lr;
    int row = (idx < N) ? perm[idx] : -1;   // degree-balanced schedule

    if (row >= 0) {
        int start = row ? row_end[row - 1] : 0;
        int end   = row_end[row];
        const uint4* xbv = reinterpret_cast<const uint4*>(xb);
        float acc[8] = {0.f, 0.f, 0.f, 0.f, 0.f, 0.f, 0.f, 0.f};
        int e = start;
        for (; e + 3 < end; e += 4) {  // 4 gathers in flight (16B each)
            int2 p[4]; uint4 g[4];
#pragma unroll
            for (int k = 0; k < 4; k++) p[k] = pairs[e + k];
#pragma unroll
            for (int k = 0; k < 4; k++) g[k] = xbv[(size_t)p[k].x * Q + q];
#pragma unroll
            for (int k = 0; k < 4; k++) {
                float v = __int_as_float(p[k].y);
                float lo, hi;
                unpack2(g[k].x, lo, hi); acc[0] += v * lo; acc[1] += v * hi;
                unpack2(g[k].y, lo, hi); acc[2] += v * lo; acc[3] += v * hi;
                unpack2(g[k].z, lo, hi); acc[4] += v * lo; acc[5] += v * hi;
                unpack2(g[k].w, lo, hi); acc[6] += v * lo; acc[7] += v * hi;
            }
        }
        for (; e < end; e++) {
            int2 p0 = pairs[e];
            uint4 g0 = xbv[(size_t)p0.x * Q + q];
            float v0 = __int_as_float(p0.y);
            float lo, hi;
            unpack2(g0.x, lo, hi); acc[0] += v0 * lo; acc[1] += v0 * hi;
            unpack2(g0.y, lo, hi); acc[2] += v0 * lo; acc[3] += v0 * hi;
            unpack2(g0.z, lo, hi); acc[4] += v0 * lo; acc[5] += v0 * hi;
            unpack2(g0.w, lo, hi); acc[6] += v0 * lo; acc[7] += v0 * hi;
        }
        uint4 xr = xbv[(size_t)row * Q + q];
        float xf[8];
        unpack2(xr.x, xf[0], xf[1]);
        unpack2(xr.y, xf[2], xf[3]);
        unpack2(xr.z, xf[4], xf[5]);
        unpack2(xr.w, xf[6], xf[7]);
        uint4 s1, s2;
        s1.x = pack2(xf[0] + acc[0], xf[1] + acc[1]);
        s1.y = pack2(xf[2] + acc[2], xf[3] + acc[3]);
        s1.z = pack2(xf[4] + acc[4], xf[5] + acc[5]);
        s1.w = pack2(xf[6] + acc[6], xf[7] + acc[7]);
        s2.x = pack2(xf[0] * acc[0], xf[1] * acc[1]);
        s2.y = pack2(xf[2] * acc[2], xf[3] * acc[3]);
        s2.z = pack2(xf[4] * acc[4], xf[5] * acc[5]);
        s2.w = pack2(xf[6] * acc[6], xf[7] * acc[7]);
        *reinterpret_cast<uint4*>(&hb[0][lr][q * 8]) = s1;
        *reinterpret_cast<uint4*>(&hb[1][lr][q * 8]) = s2;
    }
    __syncthreads();
    if (row < 0) return;

    // interleaved outputs: j = q + Q*jj (conflict-free W reads)
    float a1[4], a2[4];
#pragma unroll
    for (int jj = 0; jj < 4; jj++) {
        a1[jj] = b1[q + Q * jj];
        a2[jj] = b2[q + Q * jj];
    }
    const uint4* h1r = reinterpret_cast<const uint4*>(&hb[0][lr][0]);
    const uint4* h2r = reinterpret_cast<const uint4*>(&hb[1][lr][0]);
#pragma unroll
    for (int c = 0; c < DIN / 8; c++) {
        uint4 u1 = h1r[c], u2 = h2r[c];
        float f1[8], f2[8];
        unpack2(u1.x, f1[0], f1[1]); unpack2(u1.y, f1[2], f1[3]);
        unpack2(u1.z, f1[4], f1[5]); unpack2(u1.w, f1[6], f1[7]);
        unpack2(u2.x, f2[0], f2[1]); unpack2(u2.y, f2[2], f2[3]);
        unpack2(u2.z, f2[4], f2[5]); unpack2(u2.w, f2[6], f2[7]);
#pragma unroll
        for (int jj = 0; jj < 4; jj++) {
            int j = q + Q * jj;
            const float4* w1p = reinterpret_cast<const float4*>(&sW1[j * LDW + c * 8]);
            const float4* w2p = reinterpret_cast<const float4*>(&sW2[j * LDW + c * 8]);
            float4 wa = w1p[0], wb = w1p[1];
            float4 wc = w2p[0], wd = w2p[1];
            a1[jj] += f1[0] * wa.x + f1[1] * wa.y + f1[2] * wa.z + f1[3] * wa.w
                    + f1[4] * wb.x + f1[5] * wb.y + f1[6] * wb.z + f1[7] * wb.w;
            a2[jj] += f2[0] * wc.x + f2[1] * wc.y + f2[2] * wc.z + f2[3] * wc.w
                    + f2[4] * wd.x + f2[5] * wd.y + f2[6] * wd.z + f2[7] * wd.w;
        }
    }
    float y[4], nrm = 0.f;
#pragma unroll
    for (int jj = 0; jj < 4; jj++) {
        y[jj] = leaky(a1[jj]) + leaky(a2[jj]);
        nrm += y[jj] * y[jj];
    }
#pragma unroll
    for (int m = 1; m < Q; m <<= 1) nrm += __shfl_xor(nrm, m, 64);
    float inv = 1.0f / fmaxf(sqrtf(nrm), 1e-12f);
    if (xnextb) {
#pragma unroll
        for (int jj = 0; jj < 4; jj++)
            xnextb[(size_t)row * DOUT + q + Q * jj] = f2bf_rne(y[jj]);
    }
    float* o = out + (size_t)row * 112 + out_col0;
#pragma unroll
    for (int jj = 0; jj < 4; jj++) o[q + Q * jj] = y[jj] * inv;
}

// ---------------- f32 pull + layer (tiny-ws fallback) ----------------
template<int DIN, int DOUT>
__global__ __launch_bounds__(256) void pull_layer_kernel(
    const float* __restrict__ x, const int2* __restrict__ pairs,
    const int* __restrict__ row_end,
    const float* __restrict__ W1, const float* __restrict__ b1,
    const float* __restrict__ W2, const float* __restrict__ b2,
    float* __restrict__ xnext, float* __restrict__ out, int out_col0, int N) {
    constexpr int Q   = DIN / 4;
    constexpr int RPB = 256 / Q;
    constexpr int LD  = DIN + 4;
    constexpr int LD4 = LD / 4;
    static_assert(DOUT == 2 * Q, "thread owns exactly 2 output dims");

    __shared__ float sW1[DOUT * LD];
    __shared__ float sW2[DOUT * LD];
    __shared__ float hb[2][RPB][LD];

    for (int idx = threadIdx.x; idx < DOUT * DIN; idx += 256) {
        int j = idx / DIN, k = idx % DIN;
        sW1[j * LD + k] = W1[idx];
        sW2[j * LD + k] = W2[idx];
    }

    int lr  = threadIdx.x / Q;
    int q   = threadIdx.x % Q;
    int row = blockIdx.x * RPB + lr;

    if (row < N) {
        int start = row ? row_end[row - 1] : 0;
        int end   = row_end[row];
        const float4* xv = reinterpret_cast<const float4*>(x);
        float4 acc = make_float4(0.f, 0.f, 0.f, 0.f);
        int e = start;
        for (; e + 3 < end; e += 4) {
            int2 p0 = pairs[e];
            int2 p1 = pairs[e + 1];
            int2 p2 = pairs[e + 2];
            int2 p3 = pairs[e + 3];
            float4 g0 = xv[(size_t)p0.x * Q + q];
            float4 g1 = xv[(size_t)p1.x * Q + q];
            float4 g2 = xv[(size_t)p2.x * Q + q];
            float4 g3 = xv[(size_t)p3.x * Q + q];
            float v0 = __int_as_float(p0.y), v1 = __int_as_float(p1.y);
            float v2 = __int_as_float(p2.y), v3 = __int_as_float(p3.y);
            acc.x += v0 * g0.x; acc.y += v0 * g0.y; acc.z += v0 * g0.z; acc.w += v0 * g0.w;
            acc.x += v1 * g1.x; acc.y += v1 * g1.y; acc.z += v1 * g1.z; acc.w += v1 * g1.w;
            acc.x += v2 * g2.x; acc.y += v2 * g2.y; acc.z += v2 * g2.z; acc.w += v2 * g2.w;
            acc.x += v3 * g3.x; acc.y += v3 * g3.y; acc.z += v3 * g3.z; acc.w += v3 * g3.w;
        }
        for (; e < end; e++) {
            int2 p0 = pairs[e];
            float4 g0 = xv[(size_t)p0.x * Q + q];
            float v0 = __int_as_float(p0.y);
            acc.x += v0 * g0.x; acc.y += v0 * g0.y; acc.z += v0 * g0.z; acc.w += v0 * g0.w;
        }
        float4 xr = xv[(size_t)row * Q + q];
        float4 h1 = make_float4(xr.x + acc.x, xr.y + acc.y, xr.z + acc.z, xr.w + acc.w);
        float4 h2 = make_float4(xr.x * acc.x, xr.y * acc.y, xr.z * acc.z, xr.w * acc.w);
        *reinterpret_cast<float4*>(&hb[0][lr][q * 4]) = h1;
        *reinterpret_cast<float4*>(&hb[1][lr][q * 4]) = h2;
    }
    __syncthreads();
    if (row >= N) return;

    float a0 = b1[q], a1 = b1[q + Q], a2 = b2[q], a3 = b2[q + Q];
    const float4* w1v = reinterpret_cast<const float4*>(sW1);
    const float4* w2v = reinterpret_cast<const float4*>(sW2);
    const float4* h1v = reinterpret_cast<const float4*>(&hb[0][lr][0]);
    const float4* h2v = reinterpret_cast<const float4*>(&hb[1][lr][0]);
#pragma unroll
    for (int k4 = 0; k4 < DIN / 4; k4++) {
        float4 h1 = h1v[k4];
        float4 h2 = h2v[k4];
        float4 wa = w1v[q * LD4 + k4];
        float4 wb = w1v[(q + Q) * LD4 + k4];
        float4 wc = w2v[q * LD4 + k4];
        float4 wd = w2v[(q + Q) * LD4 + k4];
        a0 += h1.x * wa.x + h1.y * wa.y + h1.z * wa.z + h1.w * wa.w;
        a1 += h1.x * wb.x + h1.y * wb.y + h1.z * wb.z + h1.w * wb.w;
        a2 += h2.x * wc.x + h2.y * wc.y + h2.z * wc.z + h2.w * wc.w;
        a3 += h2.x * wd.x + h2.y * wd.y + h2.z * wd.z + h2.w * wd.w;
    }
    float y0 = leaky(a0) + leaky(a2);
    float y1 = leaky(a1) + leaky(a3);
    float nrm = y0 * y0 + y1 * y1;
#pragma unroll
    for (int m = 1; m < Q; m <<= 1) nrm += __shfl_xor(nrm, m, 64);
    float inv = 1.0f / fmaxf(sqrtf(nrm), 1e-12f);
    if (xnext) {
        xnext[(size_t)row * DOUT + q]     = y0;
        xnext[(size_t)row * DOUT + q + Q] = y1;
    }
    float* o = out + (size_t)row * 112 + out_col0;
    o[q]     = y0 * inv;
    o[q + Q] = y1 * inv;
}

extern "C" void kernel_launch(void* const* d_in, const int* in_sizes, int n_in,
                              void* d_out, int out_size, void* d_ws, size_t ws_size,
                              hipStream_t stream) {
    const float* Eemb = (const float*)d_in[0];
    const float* ev   = (const float*)d_in[1];
    const int*   rows = (const int*)d_in[2];
    const int*   cols = (const int*)d_in[3];
    const float* W1_0 = (const float*)d_in[4];
    const float* b1_0 = (const float*)d_in[5];
    const float* W2_0 = (const float*)d_in[6];
    const float* b2_0 = (const float*)d_in[7];
    const float* W1_1 = (const float*)d_in[8];
    const float* b1_1 = (const float*)d_in[9];
    const float* W2_1 = (const float*)d_in[10];
    const float* b2_1 = (const float*)d_in[11];
    float* out = (float*)d_out;

    int N  = in_sizes[0] / 64;
    int NE = in_sizes[1];
    int P  = (N + PROWS - 1) >> PSHIFT;   // 293

    size_t pairs_b  = (size_t)NE * sizeof(int2);
    size_t rowend_b = ((size_t)N * sizeof(int) + 255) & ~(size_t)255;
    size_t small_b  = (PBINS + (PBINS + 1) + PBINS + 256 + 256) * sizeof(int) + 256;
    small_b = (small_b + 255) & ~(size_t)255;
    size_t ebf_b    = ((size_t)N * 64 * sizeof(unsigned short) + 255) & ~(size_t)255;
    size_t x1b_b    = ((size_t)N * 32 * sizeof(unsigned short) + 255) & ~(size_t)255;
    size_t perm_b   = (size_t)N * sizeof(int);

    char* base = (char*)d_ws;
    int2*  pairs   = (int2*)base;
    int*   row_end = (int*)(base + pairs_b);
    int*   pcnt    = (int*)(base + pairs_b + rowend_b);
    int*   pbase   = pcnt + PBINS;
    int*   gcur    = pbase + PBINS + 1;
    int*   dcnt    = gcur + PBINS;
    int*   dcur    = dcnt + 256;
    unsigned short* Ebf = (unsigned short*)(base + pairs_b + rowend_b + small_b);
    unsigned short* x1b = (unsigned short*)(base + pairs_b + rowend_b + small_b + ebf_b);
    int*   perm    = (int*)(base + pairs_b + rowend_b + small_b + ebf_b + x1b_b);
    float* x1      = (float*)(base + pairs_b + rowend_b + small_b);  // fallback layout

    bool use_bf = ws_size >= pairs_b + rowend_b + small_b + ebf_b + x1b_b + perm_b;

    int2* tmp = (int2*)d_out;  // 38.4MB scratch, dead until copy_E

    hipMemsetAsync(pcnt, 0, PBINS * sizeof(int), stream);
    hipMemsetAsync(dcnt, 0, 256 * sizeof(int), stream);
    part_hist_kernel<<<256, 1024, P * sizeof(int), stream>>>(rows, pcnt, NE, P);
    part_scan_kernel<<<1, PBINS, 0, stream>>>(pcnt, pbase, gcur, P, NE);
    group_flush_kernel<<<(NE + GF_E - 1) / GF_E, GF_T, 0, stream>>>(
        rows, cols, ev, gcur, tmp, NE, P);
    row_sort_kernel<<<P, PROWS, 0, stream>>>(tmp, pairs, pbase, row_end,
                                             use_bf ? dcnt : nullptr, N);

    copy_E_kernel<<<(N * 16 + 255) / 256, 256, 0, stream>>>(
        Eemb, out, use_bf ? Ebf : nullptr, N);

    if (use_bf) {
        deg_scan_kernel<<<1, 256, 0, stream>>>(dcnt, dcur);
        deg_scatter_kernel<<<(N + DS_R - 1) / DS_R, DS_T, 0, stream>>>(
            row_end, dcur, perm, N);

        pull_layer_b2_kernel<64, 32><<<(N + 31) / 32, 256, 0, stream>>>(
            Ebf, pairs, row_end, perm, W1_0, b1_0, W2_0, b2_0, x1b, out, 64, N);
        pull_layer_b2_kernel<32, 16><<<(N + 63) / 64, 256, 0, stream>>>(
            x1b, pairs, row_end, perm, W1_1, b1_1, W2_1, b2_1, nullptr, out, 96, N);
    } else {
        pull_layer_kernel<64, 32><<<(N + 15) / 16, 256, 0, stream>>>(
            Eemb, pairs, row_end, W1_0, b1_0, W2_0, b2_0, x1, out, 64, N);
        pull_layer_kernel<32, 16><<<(N + 31) / 32, 256, 0, stream>>>(
            x1, pairs, row_end, W1_1, b1_1, W2_1, b2_1, nullptr, out, 96, N);
    }
}